// Round 3
// 2077.448 us; speedup vs baseline: 1.0510x; 1.0510x over previous
//
#include <hip/hip_runtime.h>
#include <math.h>

#define NN 4096
#define TT 64
#define HH 128
#define NNP 4160            // hinT row stride (shorts): 8320B kills 8KB L2 set-aliasing
#define SPLITS 16
#define KPB (NN / SPLITS)   // 256 keys per phase-A block
#define KT 32
#define NTILES (KPB / KT)   // 8
#define SCALE 0.08838834764831845f   // 1/sqrt(128)
#define CSHIFT 16.0f

typedef __attribute__((ext_vector_type(8))) short short8;
typedef __attribute__((ext_vector_type(4))) float f32x4;
typedef unsigned long long u64;
#define MFMA(a, b, c)   __builtin_amdgcn_mfma_f32_16x16x32_bf16((a), (b), (c), 0, 0, 0)

// ---- bf16 helpers (RNE) ----
__device__ __forceinline__ short f2b(float f) {
    union { float f; unsigned u; } v; v.f = f;
    unsigned r = v.u + 0x7fffu + ((v.u >> 16) & 1u);
    return (short)(r >> 16);
}
__device__ __forceinline__ float b2f(short s) {
    union { unsigned u; float f; } v; v.u = ((unsigned)(unsigned short)s) << 16;
    return v.f;
}
// Wave-local LDS fence (R7/R8-proven): completes ds ops + blocks compiler
// reordering of cross-lane LDS accesses without a block barrier.
__device__ __forceinline__ void lds_fence() {
    __asm__ __volatile__("s_waitcnt lgkmcnt(0)" ::: "memory");
}

// ===========================================================================
// hinT column permutation sigma (within each 32-column group):
//   column c holds node  sigma(c) = (c&4) ? 16 + 4*(c>>3) + (c&3)
//                                         :      4*(c>>3) + (c&3)
// Writers (prep/fuse) place node kk at column
//   inv_sigma(kk) = ((kk>>2)&3)*8 + ((kk>>4)&1)*4 + (kk&3).
// Why: after swapped QK^T (st = MFMA(K,Q), D[key][q]), lane (ln,g) holds the
// 8 P-values of query qt*16+ln for keys {4g..4g+3, 16+4g..16+4g+3} — which is
// EXACTLY a 16x16x32 PV A-fragment under sigma on the key axis.  The PV key
// axis is a dot product, so permuting BOTH P-slots and V-slots by sigma is
// mathematically free; baking sigma into hinT storage means attention stages
// V contiguously and P never touches LDS (no PtS round-trip, 1 barrier/tile).
// All MFMA fragment conventions used here are the baseline-proven 16x16x32
// ones (A/B: row|col = lane&15, k = (lane>>4)*8+e; C/D: col = lane&15,
// row = (lane>>4)*4 + reg).
// ===========================================================================

// ===========================================================================
// prep: once per launch. bf16 weight transposes; hp = b_proj (h0=0);
// hinT (padded stride NNP, sigma-permuted columns) from x[:,0], m[:,0].
// ===========================================================================
__global__ __launch_bounds__(256) void prep_kernel(
    const float* __restrict__ x_seq, const float* __restrict__ m_seq,
    const float* __restrict__ W_in,  const float* __restrict__ b_in,
    const float* __restrict__ W_proj,const float* __restrict__ b_proj,
    const float* __restrict__ W_gcn,
    short* __restrict__ hp, short* __restrict__ hinT,
    short* __restrict__ WgT, short* __restrict__ WpT)
{
    const int b = blockIdx.x, tid = threadIdx.x;
    if (b < 256) {
        const int n0 = b * 16;
        for (int i = tid; i < 16 * HH; i += 256) {
            const int q = i >> 7, j = i & 127, n = n0 + q;
            hp[n * HH + j] = f2b(b_proj[j]);
            float hv = x_seq[n * TT] * W_in[j] + m_seq[n * TT] * W_in[HH + j] + b_in[j];
            hv = hv > 0.f ? hv : 0.f;
            // col = (n & ~31) | inv_sigma(n & 31)
            const int col = (n & ~31) | (((n >> 2) & 3) << 3) | (((n >> 4) & 1) << 2) | (n & 3);
            hinT[(size_t)j * NNP + col] = f2b(hv);
        }
    } else {
        const int wb = b - 256;
        #pragma unroll
        for (int k = 0; k < 4; ++k) {
            const int idx = wb * 1024 + k * 256 + tid;   // = n*128 + kk
            const int n = idx >> 7, kk = idx & 127;
            WgT[idx] = f2b(W_gcn[kk * HH + n]);
            WpT[idx] = f2b(W_proj[kk * HH + n]);
        }
    }
}

// ===========================================================================
// Phase A: attention partials. 256 blocks (16 qg x 16 splits) x 512 thr
// (8 waves). Wave w owns 32 q rows (2 q-tiles); all waves share the block's
// 256-key slice via LDS-staged double-buffered K/V tiles, ONE barrier/tile.
//   QK^T swapped: st = MFMA(kf, qf) -> D[key][q].  P is rounded to bf16 in
//   registers (f2b — bit-identical to baseline numerics) and fed straight to
//   PV as the A-fragment via the sigma key-permutation baked into hinT.
// Partial O is written as bf16 through a per-wave LDS bounce (coalesced
// 16B/lane stores); l stays fp32. Kernel boundary publishes state.
// ===========================================================================
__global__ __launch_bounds__(512, 2) void attn_kernel(
    const short* __restrict__ hp, const short* __restrict__ hinT,
    short* __restrict__ OpartB, float* __restrict__ lpart)
{
    __shared__ __align__(16) char pool[37888];
    short* KtS = (short*)pool;                  // [2][32*136]  17408 B
    short* VtS = (short*)(pool + 17408);        // [2][128*40]  20480 B

    const int tid  = threadIdx.x;
    const int wave = tid >> 6, lane = tid & 63;
    const int ln = lane & 15, g = lane >> 4;
    const int qg = blockIdx.x >> 4, split = blockIdx.x & 15;
    const int q0 = qg * 256 + wave * 32;
    const int kbase = split * KPB;

    // staging thread maps (512 threads, 16B/lane coalesced)
    const int krow = tid >> 4, kcol = (tid & 15) * 8;   // 32 rows x 128 shorts
    const int vrow = tid >> 2, vcol = (tid & 3) * 8;    // 128 rows x 32 shorts

    // Q fragments (B-operand in swapped QK^T): 2 q-tiles, proven layout
    short8 qf[2][4];
    #pragma unroll
    for (int qt = 0; qt < 2; ++qt)
        #pragma unroll
        for (int kc = 0; kc < 4; ++kc)
            qf[qt][kc] = *(const short8*)&hp[(q0 + qt * 16 + ln) * HH + kc * 32 + g * 8];

    f32x4 oacc[2][8] = {};   // O[q = qt*16 + g*4 + r][d = dt*16 + ln]
    float lsum[2] = {0.f, 0.f};

    short8 ksA, vsA;
    auto load_tile = [&](int kt_) {
        const int kb = kbase + kt_ * KT;
        ksA = *(const short8*)&hp  [(kb + krow) * HH + kcol];
        vsA = *(const short8*)&hinT[(size_t)vrow * NNP + kb + vcol];
    };
    auto store_tile = [&](int b) {
        *(short8*)&KtS[b * 4352 + krow * 136 + kcol] = ksA;
        *(short8*)&VtS[b * 5120 + vrow * 40 + vcol]  = vsA;
    };

    load_tile(0);
    store_tile(0);

    for (int kt = 0; kt < NTILES; ++kt) {
        const int b = kt & 1;
        __syncthreads();   // buf b staged; prev iter's frag reads drained (WAR)

        // K fragments (A-operand): 2 key-tiles, baseline-identical read pattern
        short8 kf[2][4], vf[8];
        #pragma unroll
        for (int kt2 = 0; kt2 < 2; ++kt2)
            #pragma unroll
            for (int kc = 0; kc < 4; ++kc)
                kf[kt2][kc] = *(const short8*)&KtS[b * 4352 + (kt2 * 16 + ln) * 136 + kc * 32 + g * 8];
        // V^T fragments (B-operand), slot space (sigma already in hinT storage)
        #pragma unroll
        for (int dt = 0; dt < 8; ++dt)
            vf[dt] = *(const short8*)&VtS[b * 5120 + (dt * 16 + ln) * 40 + g * 8];

        if (kt + 1 < NTILES) load_tile(kt + 1);   // global -> regs, overlaps compute

        // swapped scores: st[kt2][qt][r] = S[key = kt2*16 + g*4 + r][q = qt*16 + ln]
        f32x4 st[2][2] = {};
        __builtin_amdgcn_s_setprio(1);
        #pragma unroll
        for (int kt2 = 0; kt2 < 2; ++kt2)
            #pragma unroll
            for (int qt = 0; qt < 2; ++qt)
                #pragma unroll
                for (int kc = 0; kc < 4; ++kc)
                    st[kt2][qt] = MFMA(kf[kt2][kc], qf[qt][kc], st[kt2][qt]);
        __builtin_amdgcn_s_setprio(0);

        // fixed-shift softmax numerators, rounded bf16 in registers.
        // pa[qt] element e holds key sigma(g*8+e) of query qt*16+ln:
        //   e=0..3 -> st[0][qt][e] (keys 4g+e), e=4..7 -> st[1][qt][e-4].
        // l sums the ROUNDED values (self-consistency with O's bf16 MFMA).
        short8 pa[2];
        #pragma unroll
        for (int qt = 0; qt < 2; ++qt) {
            short8 paq;
            #pragma unroll
            for (int e = 0; e < 8; ++e) {
                const float s = (e < 4) ? st[0][qt][e] : st[1][qt][e - 4];
                const short pb = f2b(__expf(s * SCALE - CSHIFT));
                lsum[qt] += b2f(pb);
                paq[e] = pb;
            }
            pa[qt] = paq;
        }

        if (kt + 1 < NTILES) store_tile(b ^ 1);

        // PV: pa[qt] is exactly the A-fragment in slot space
        __builtin_amdgcn_s_setprio(1);
        #pragma unroll
        for (int qt = 0; qt < 2; ++qt)
            #pragma unroll
            for (int dt = 0; dt < 8; ++dt)
                oacc[qt][dt] = MFMA(pa[qt], vf[dt], oacc[qt][dt]);
        __builtin_amdgcn_s_setprio(0);
    }

    __syncthreads();   // all waves' LDS frag reads done -> pool reusable as bounce

    // l reduction over the g dimension (4 lanes per query: ln, ln+16, ln+32, ln+48)
    #pragma unroll
    for (int qt = 0; qt < 2; ++qt) {
        float l = lsum[qt];
        l += __shfl_xor(l, 16);
        l += __shfl_xor(l, 32);
        if (lane < 16) lpart[split * NN + q0 + qt * 16 + lane] = l;
    }

    // O partials -> bf16 via per-wave LDS bounce (coalesced 16B/lane stores)
    short* bounce = (short*)pool + wave * 2048;   // 4KB/wave in dead Kt/Vt
    #pragma unroll
    for (int qt = 0; qt < 2; ++qt) {
        #pragma unroll
        for (int dt = 0; dt < 8; ++dt)
            #pragma unroll
            for (int r = 0; r < 4; ++r)
                bounce[(g * 4 + r) * 128 + dt * 16 + ln] = f2b(oacc[qt][dt][r]);
        lds_fence();   // RAW: cross-lane bounce writes before row reads
        #pragma unroll
        for (int sub = 0; sub < 4; ++sub) {
            const int qrow = sub * 4 + (lane >> 4), chunk = lane & 15;
            const short8 rd = *(const short8*)&bounce[qrow * 128 + chunk * 8];
            *(short8*)&OpartB[((size_t)split * NN + q0 + qt * 16 + qrow) * HH + chunk * 8] = rd;
        }
        lds_fence();   // WAR before next qt overwrites the bounce
    }
}

// ===========================================================================
// Phase B: merge 16 bf16 partials -> msg; h_new = relu(msg@Wg+b_gcn+h_in(t));
// pred -> out[:,t]; h_proj(t+1) -> hp; h_in(t+1) -> hinT (recomputed, bf16-
// rounding parity; columns stored sigma-permuted). 256 blocks x 256 thr.
// ===========================================================================
__global__ __launch_bounds__(256) void fuse_kernel(
    const short* __restrict__ OpartB, const float* __restrict__ lpart,
    short* __restrict__ hp, short* __restrict__ hinT,
    const short* __restrict__ WgT, const short* __restrict__ WpT,
    const float* __restrict__ b_gcn, const float* __restrict__ b_proj,
    const float* __restrict__ W_out, const float* __restrict__ b_out,
    const float* __restrict__ x_seq, const float* __restrict__ m_seq,
    const float* __restrict__ W_in,  const float* __restrict__ b_in,
    float* __restrict__ out, int t)
{
    __shared__ __align__(16) short msgb[16 * 136];
    __shared__ __align__(16) short hnb[16 * 136];
    __shared__ __align__(16) short hintb[128 * 16];
    __shared__ float larr[16];
    __shared__ float ppd[4 * 16];

    const int tid = threadIdx.x;
    const int wave = tid >> 6, lane = tid & 63;
    const int ln = lane & 15, g = lane >> 4;
    const int qb = blockIdx.x * 16;

    if (tid < 16) {
        float l = 0.f;
        #pragma unroll
        for (int sp = 0; sp < SPLITS; ++sp) l += lpart[sp * NN + qb + tid];
        larr[tid] = 1.0f / l;
    }
    __syncthreads();

    // merge 16 bf16 partials -> msg (short8 coalesced reads, fp32 accumulate)
    {
        const int q = tid >> 4, c8 = (tid & 15) * 8;   // 256 thr = 16q x 16 chunks
        float s[8] = {0.f, 0.f, 0.f, 0.f, 0.f, 0.f, 0.f, 0.f};
        #pragma unroll
        for (int sp = 0; sp < SPLITS; ++sp) {
            const short8 v = *(const short8*)&OpartB[((size_t)sp * NN + qb + q) * HH + c8];
            #pragma unroll
            for (int k = 0; k < 8; ++k) s[k] += b2f(v[k]);
        }
        const float inv = larr[q];
        short* mp = &msgb[q * 136 + c8];
        #pragma unroll
        for (int k = 0; k < 8; ++k) mp[k] = f2b(s[k] * inv);
    }
    __syncthreads();

    // GEMM1: h_new = relu(msg @ W_gcn + b_gcn + h_in(t)); pred partials
    short8 af[4];
    #pragma unroll
    for (int kc = 0; kc < 4; ++kc)
        af[kc] = *(const short8*)&msgb[ln * 136 + kc * 32 + g * 8];
    float pr[4] = {0.f, 0.f, 0.f, 0.f};
    #pragma unroll
    for (int ni = 0; ni < 2; ++ni) {
        const int nt = wave * 2 + ni;
        f32x4 c = {};
        #pragma unroll
        for (int kc = 0; kc < 4; ++kc)
            c = MFMA(af[kc], *(const short8*)&WgT[(nt * 16 + ln) * HH + kc * 32 + g * 8], c);
        const int j = nt * 16 + ln;
        const float bg = b_gcn[j], wo = W_out[j];
        const float wj0 = W_in[j], wj1 = W_in[HH + j], bj = b_in[j];
        #pragma unroll
        for (int r = 0; r < 4; ++r) {
            const int q = g * 4 + r;
            float hv = x_seq[(qb + q) * TT + t] * wj0 + m_seq[(qb + q) * TT + t] * wj1 + bj;
            hv = hv > 0.f ? hv : 0.f;
            float v = c[r] + bg + b2f(f2b(hv));
            v = v > 0.f ? v : 0.f;
            hnb[q * 136 + j] = f2b(v);
            pr[r] += v * wo;
        }
    }
    #pragma unroll
    for (int r = 0; r < 4; ++r) {
        float p = pr[r];
        p += __shfl_xor(p, 1); p += __shfl_xor(p, 2);
        p += __shfl_xor(p, 4); p += __shfl_xor(p, 8);
        if (ln == 0) ppd[wave * 16 + g * 4 + r] = p;
    }
    __syncthreads();   // hnb + ppd complete

    if (tid < 16)
        out[(qb + tid) * TT + t] = ppd[tid] + ppd[16 + tid] + ppd[32 + tid] + ppd[48 + tid] + b_out[0];

    if (t < TT - 1) {
        // GEMM2: h_proj(t+1) = h_new @ W_proj + b_proj -> hp
        short8 hf[4];
        #pragma unroll
        for (int kc = 0; kc < 4; ++kc)
            hf[kc] = *(const short8*)&hnb[ln * 136 + kc * 32 + g * 8];
        #pragma unroll
        for (int ni = 0; ni < 2; ++ni) {
            const int nt = wave * 2 + ni;
            f32x4 c = {};
            #pragma unroll
            for (int kc = 0; kc < 4; ++kc)
                c = MFMA(hf[kc], *(const short8*)&WpT[(nt * 16 + ln) * HH + kc * 32 + g * 8], c);
            const float bp = b_proj[nt * 16 + ln];
            #pragma unroll
            for (int r = 0; r < 4; ++r)
                hp[(qb + g * 4 + r) * HH + nt * 16 + ln] = f2b(c[r] + bp);
        }

        // h_in(t+1): LDS transpose then 8B-chunk stores into sigma-permuted
        // hinT columns.  Each aligned 4-node chunk {qb+off..+3} lands at
        // column tcol = (nb & ~31) | inv_sigma(nb & 31), nb = qb+off
        // (inv_sigma maps aligned-4 chunks to aligned-4 chunks).
        for (int i = tid; i < 16 * HH; i += 256) {
            const int q = i >> 7, j = i & 127;
            float hv = x_seq[(qb + q) * TT + t + 1] * W_in[j]
                     + m_seq[(qb + q) * TT + t + 1] * W_in[HH + j] + b_in[j];
            hv = hv > 0.f ? hv : 0.f;
            hintb[j * 16 + q] = f2b(hv);
        }
        __syncthreads();
        for (int c = tid; c < 512; c += 256) {
            const int j = c >> 2, off = (c & 3) * 4;
            const int nb = qb + off;
            const int tcol = (nb & ~31) | (((nb >> 2) & 3) << 3) | (((nb >> 4) & 1) << 2);
            *(u64*)&hinT[(size_t)j * NNP + tcol] = *(const u64*)&hintb[j * 16 + off];
        }
    }
}

// ===========================================================================
extern "C" void kernel_launch(void* const* d_in, const int* in_sizes, int n_in,
                              void* d_out, int out_size, void* d_ws, size_t ws_size,
                              hipStream_t stream) {
    const float* x_seq  = (const float*)d_in[0];
    const float* m_seq  = (const float*)d_in[1];
    const float* W_in   = (const float*)d_in[2];
    const float* b_in   = (const float*)d_in[3];
    const float* W_proj = (const float*)d_in[4];
    const float* b_proj = (const float*)d_in[5];
    const float* W_gcn  = (const float*)d_in[6];
    const float* b_gcn  = (const float*)d_in[7];
    const float* W_out  = (const float*)d_in[8];
    const float* b_out  = (const float*)d_in[9];
    float* out = (float*)d_out;

    // ws carve (~20 MB): hp | hinT(padded) | WgT | WpT | lpart | OpartB
    char* base = (char*)d_ws;
    const size_t MB = 1 << 20;
    short* hp     = (short*)(base + 0 * MB);
    short* hinT   = (short*)(base + 1 * MB);           // 128*4160*2 B
    short* WgT    = (short*)(base + 3 * MB);
    short* WpT    = (short*)(base + 3 * MB + 32768);
    float* lpart  = (float*)(base + 3 * MB + 65536);   // 16*4096*4 = 256 KB
    short* OpartB = (short*)(base + 4 * MB);           // 16*4096*128*2 = 16 MB

    prep_kernel<<<272, 256, 0, stream>>>(x_seq, m_seq, W_in, b_in, W_proj, b_proj,
                                         W_gcn, hp, hinT, WgT, WpT);

    for (int t = 0; t < TT; ++t) {
        attn_kernel<<<(NN / 256) * SPLITS, 512, 0, stream>>>(hp, hinT, OpartB, lpart);
        fuse_kernel<<<NN / 16, 256, 0, stream>>>(OpartB, lpart, hp, hinT,
                                                 WgT, WpT, b_gcn, b_proj, W_out, b_out,
                                                 x_seq, m_seq, W_in, b_in, out, t);
    }
}